// Round 2
// baseline (610.501 us; speedup 1.0000x reference)
//
#include <hip/hip_runtime.h>
#include <hip/hip_cooperative_groups.h>

namespace cg = cooperative_groups;

typedef unsigned short u16;
typedef __attribute__((ext_vector_type(8))) short bf16x8;
typedef __attribute__((ext_vector_type(4))) float f32x4;

#define B_   128
#define P_   2048
#define NC_  10
#define F_   160      // NC*CLO
#define PPB  8        // p values per block
#define NBLK 256      // one block per CU, cooperative
#define NTHR 512
#define XQS  1032     // shorts per x (p,q)-plane: 128 rows * 8 + 8 pad (keeps q-planes bank-offset)
#define WQS  1288     // shorts per w (p,q)-plane: 160 rows * 8 + 8 pad
#define WBASE 33024   // = 32 * XQS, short offset of w region
#define SMEM_BYTES 148480  // (33024 + 32*1288) * 2

__device__ __forceinline__ u16 f2bf(float f) {
    union { float f; unsigned u; } v; v.f = f;
    unsigned r = v.u + 0x7FFFu + ((v.u >> 16) & 1u);   // RNE
    return (u16)(r >> 16);
}
__device__ __forceinline__ float bf2f(u16 h) {
    union { unsigned u; float f; } v; v.u = ((unsigned)h) << 16;
    return v.f;
}

extern __shared__ u16 sm[];

// One routing pass over this block's 8 resident p-tiles.
// MODE 0: c = 0.1 uniform. MODE 1: t = u.v0, save to bias regs, softmax(t).
// MODE 2: t = bias + u.v1, softmax(t). Writes bf16 partial s for this block.
template<int MODE>
__device__ __forceinline__ void routing_pass(
    const float* __restrict__ vprev, u16* __restrict__ s_part,
    float (&bias)[PPB][NC_], int q, int col, int b, int blk)
{
    float s_acc[NC_][4];
#pragma unroll
    for (int n = 0; n < NC_; ++n)
#pragma unroll
        for (int r = 0; r < 4; ++r) s_acc[n][r] = 0.f;

#pragma unroll
    for (int pp = 0; pp < PPB; ++pp) {
        const u16* xq = sm + (pp * 4 + q) * XQS;
        const u16* wq = sm + WBASE + (pp * 4 + q) * WQS;
        bf16x8 bfrag = *(const bf16x8*)(xq + b * 8);   // B[k=q*8+j][n=col] = x[b][k]
        if (MODE == 0) {
#pragma unroll
            for (int n = 0; n < NC_; ++n) {
                bf16x8 afrag = *(const bf16x8*)(wq + (n * 16 + col) * 8);
                f32x4 z = {0.f, 0.f, 0.f, 0.f};
                f32x4 acc = __builtin_amdgcn_mfma_f32_16x16x32_bf16(afrag, bfrag, z, 0, 0, 0);
#pragma unroll
                for (int r = 0; r < 4; ++r) s_acc[n][r] += 0.1f * acc[r];
            }
        } else {
            float tt[NC_];
#pragma unroll
            for (int n = 0; n < NC_; ++n) {
                bf16x8 afrag = *(const bf16x8*)(wq + (n * 16 + col) * 8);
                f32x4 z = {0.f, 0.f, 0.f, 0.f};
                f32x4 acc = __builtin_amdgcn_mfma_f32_16x16x32_bf16(afrag, bfrag, z, 0, 0, 0);
                // lane holds u[b][n][k'=q*4+r] in acc[r]
                float4 vv = *(const float4*)(vprev + b * F_ + n * 16 + q * 4);
                float t = acc[0]*vv.x + acc[1]*vv.y + acc[2]*vv.z + acc[3]*vv.w;
                t += __shfl_xor(t, 16);       // reduce over q: full 16-elem dot
                t += __shfl_xor(t, 32);
                if (MODE == 1) bias[pp][n] = t;
                else           t += bias[pp][n];
                tt[n] = t;
            }
            float mx = tt[0];
#pragma unroll
            for (int n = 1; n < NC_; ++n) mx = fmaxf(mx, tt[n]);
            float den = 0.f, c[NC_];
#pragma unroll
            for (int n = 0; n < NC_; ++n) { c[n] = __expf(tt[n] - mx); den += c[n]; }
            float inv = 1.f / den;
            // recompute acc (2nd MFMA) to keep register liveness low, then weight-accumulate
#pragma unroll
            for (int n = 0; n < NC_; ++n) {
                bf16x8 afrag = *(const bf16x8*)(wq + (n * 16 + col) * 8);
                f32x4 z = {0.f, 0.f, 0.f, 0.f};
                f32x4 acc = __builtin_amdgcn_mfma_f32_16x16x32_bf16(afrag, bfrag, z, 0, 0, 0);
                float cf = c[n] * inv;
#pragma unroll
                for (int r = 0; r < 4; ++r) s_acc[n][r] += cf * acc[r];
            }
        }
    }
    u16* sp = s_part + blk * (B_ * F_);
#pragma unroll
    for (int n = 0; n < NC_; ++n) {
        u16 h[4] __attribute__((aligned(8)));
#pragma unroll
        for (int r = 0; r < 4; ++r) h[r] = f2bf(s_acc[n][r]);
        *(ushort4*)(sp + b * F_ + n * 16 + q * 4) = *(const ushort4*)h;
    }
}

// Sum bf16 partials over NBLK blocks, squash along CLO (16 consecutive f), write fp32 v.
__device__ __forceinline__ void reduce_phase(const u16* __restrict__ s_part,
                                             float* __restrict__ vout, int blk, int tid)
{
    if (tid < 80) {
        int o = blk * 80 + tid;                 // 256 blocks * 80 = 20480 outputs
        float a0 = 0.f, a1 = 0.f, a2 = 0.f, a3 = 0.f;
#pragma unroll 4
        for (int g = 0; g < NBLK; g += 4) {
            a0 += bf2f(s_part[(g    ) * (B_ * F_) + o]);
            a1 += bf2f(s_part[(g + 1) * (B_ * F_) + o]);
            a2 += bf2f(s_part[(g + 2) * (B_ * F_) + o]);
            a3 += bf2f(s_part[(g + 3) * (B_ * F_) + o]);
        }
        float a = (a0 + a1) + (a2 + a3);
        float sq = a * a;
        sq += __shfl_xor(sq, 1);
        sq += __shfl_xor(sq, 2);
        sq += __shfl_xor(sq, 4);
        sq += __shfl_xor(sq, 8);
        vout[o] = a * sq / ((1.f + sq) * sqrtf(sq));
    }
}

__global__ __launch_bounds__(NTHR, 2) void k_main(
    const float* __restrict__ tensor, const float* __restrict__ weight,
    float* __restrict__ out, u16* __restrict__ s_part,
    float* __restrict__ v0, float* __restrict__ v1)
{
    const int tid = threadIdx.x, blk = blockIdx.x;
    const int L = tid & 63;
    const int q = L >> 4, col = L & 15;
    const int b = (tid >> 6) * 16 + col;     // 8 waves x 16 cols = 128 batch rows
    const int p0 = blk * PPB;

    // ---- stage x: squash along NP, bf16, layout [p][q][b][k8] (once) ----
    {
        const int sb = tid >> 2, sq_ = tid & 3;      // thread -> (b, q-chunk)
        const float4* tg = (const float4*)tensor;
#pragma unroll
        for (int pp = 0; pp < PPB; ++pp) {
            int p = p0 + pp;
            int fi = (sb * P_ + p) * 8 + sq_ * 2;    // float4 index
            float4 va = tg[fi], vb = tg[fi + 1];
            float ss = va.x*va.x + va.y*va.y + va.z*va.z + va.w*va.w
                     + vb.x*vb.x + vb.y*vb.y + vb.z*vb.z + vb.w*vb.w;
            ss += __shfl_xor(ss, 1);                 // quad (same b) holds full row sum
            ss += __shfl_xor(ss, 2);
            float fct = ss / ((1.f + ss) * sqrtf(ss));
            u16 h[8] __attribute__((aligned(16)));
            h[0]=f2bf(va.x*fct); h[1]=f2bf(va.y*fct); h[2]=f2bf(va.z*fct); h[3]=f2bf(va.w*fct);
            h[4]=f2bf(vb.x*fct); h[5]=f2bf(vb.y*fct); h[6]=f2bf(vb.z*fct); h[7]=f2bf(vb.w*fct);
            *(uint4*)(sm + (pp * 4 + sq_) * XQS + sb * 8) = *(const uint4*)h;
        }
    }
    // ---- stage w: bf16 + transpose [k][f] -> [p][q][f][k8] (once) ----
    {
        const float4* wg = (const float4*)weight;
#pragma unroll
        for (int pp = 0; pp < PPB; ++pp) {
            int p = p0 + pp;
            for (int u_ = tid; u_ < 640; u_ += NTHR) {   // 32 k * 20 f-groups
                int k = u_ / 20, fg = u_ % 20;
                int fi = (p * 32 + k) * 40 + fg * 2;
                float4 va = wg[fi], vb = wg[fi + 1];
                u16* dst = sm + WBASE + (pp * 4 + (k >> 3)) * WQS + fg * 64 + (k & 7);
                dst[0]  = f2bf(va.x); dst[8]  = f2bf(va.y);
                dst[16] = f2bf(va.z); dst[24] = f2bf(va.w);
                dst[32] = f2bf(vb.x); dst[40] = f2bf(vb.y);
                dst[48] = f2bf(vb.z); dst[56] = f2bf(vb.w);
            }
        }
    }
    __syncthreads();

    cg::grid_group grid = cg::this_grid();
    float bias[PPB][NC_];
#pragma unroll
    for (int pp = 0; pp < PPB; ++pp)
#pragma unroll
        for (int n = 0; n < NC_; ++n) bias[pp][n] = 0.f;

    routing_pass<0>(nullptr, s_part, bias, q, col, b, blk);
    __threadfence(); grid.sync();
    reduce_phase(s_part, v0, blk, tid);
    __threadfence(); grid.sync();
    routing_pass<1>(v0, s_part, bias, q, col, b, blk);
    __threadfence(); grid.sync();
    reduce_phase(s_part, v1, blk, tid);
    __threadfence(); grid.sync();
    routing_pass<2>(v1, s_part, bias, q, col, b, blk);
    __threadfence(); grid.sync();
    reduce_phase(s_part, out, blk, tid);
}

extern "C" void kernel_launch(void* const* d_in, const int* in_sizes, int n_in,
                              void* d_out, int out_size, void* d_ws, size_t ws_size,
                              hipStream_t stream) {
    const float* tensor = (const float*)d_in[0];
    const float* weight = (const float*)d_in[1];
    float* out = (float*)d_out;
    char* ws = (char*)d_ws;

    u16*   s_part = (u16*)ws;                      // 256 * 20480 * 2 = 10,485,760 B
    float* v0     = (float*)(ws + 10485760);       // 81,920 B
    float* v1     = (float*)(ws + 10567680);       // 81,920 B

    hipFuncSetAttribute((const void*)k_main,
                        hipFuncAttributeMaxDynamicSharedMemorySize, SMEM_BYTES);
    void* args[] = { (void*)&tensor, (void*)&weight, (void*)&out,
                     (void*)&s_part, (void*)&v0, (void*)&v1 };
    hipLaunchCooperativeKernel((const void*)k_main, dim3(NBLK), dim3(NTHR),
                               args, SMEM_BYTES, stream);
}

// Round 3
// 294.837 us; speedup vs baseline: 2.0706x; 2.0706x over previous
//
#include <hip/hip_runtime.h>

typedef unsigned short u16;
typedef __attribute__((ext_vector_type(8))) short bf16x8;
typedef __attribute__((ext_vector_type(4))) float f32x4;

#define B_   128
#define P_   2048
#define NC_  10
#define F_   160      // NC*CLO
#define NBLK 512      // k_pass blocks: 2 per CU
#define PPB  4        // p-tiles per block
#define NTHR 512
#define XS   40       // x tile row stride (shorts), padded
#define WS   40       // w tile row stride (shorts), padded

__device__ __forceinline__ u16 f2bf(float f) {
    union { float f; unsigned u; } v; v.f = f;
    unsigned r = v.u + 0x7FFFu + ((v.u >> 16) & 1u);   // RNE
    return (u16)(r >> 16);
}
__device__ __forceinline__ float bf2f(u16 h) {
    union { unsigned u; float f; } v; v.u = ((unsigned)h) << 16;
    return v.f;
}

// squash along NP=32, cast bf16, write xb[p][b][k]. 4 lanes per (b,p) pair;
// wave reads 16 pairs x 128B = 2KB contiguous.
__global__ void k_squash_x(const float* __restrict__ t, u16* __restrict__ xb) {
    int g = blockIdx.x * 256 + threadIdx.x;
    int pair = g >> 2, sub = g & 3;
    int p = pair & 2047, b = pair >> 11;
    const float4* tg = (const float4*)t;
    int fi = pair * 8 + sub * 2;
    float4 va = tg[fi], vb = tg[fi + 1];
    float ss = va.x*va.x + va.y*va.y + va.z*va.z + va.w*va.w
             + vb.x*vb.x + vb.y*vb.y + vb.z*vb.z + vb.w*vb.w;
    ss += __shfl_xor(ss, 1);      // quad holds the full 32-elem sum
    ss += __shfl_xor(ss, 2);
    float fct = ss / ((1.f + ss) * sqrtf(ss));
    u16 h[8] __attribute__((aligned(16)));
    h[0]=f2bf(va.x*fct); h[1]=f2bf(va.y*fct); h[2]=f2bf(va.z*fct); h[3]=f2bf(va.w*fct);
    h[4]=f2bf(vb.x*fct); h[5]=f2bf(vb.y*fct); h[6]=f2bf(vb.z*fct); h[7]=f2bf(vb.w*fct);
    *(uint4*)(xb + (p * 128 + b) * 32 + sub * 8) = *(const uint4*)h;
}

// weight[p][k][f] fp32 -> wb[p][f][k] bf16 (transpose via LDS)
__global__ void k_wt(const float* __restrict__ w, u16* __restrict__ wb) {
    __shared__ u16 wl[32 * F_];
    int p = blockIdx.x, tid = threadIdx.x;
    const float4* wp = (const float4*)(w + p * 32 * F_);
    for (int e4 = tid; e4 < 1280; e4 += 256) {
        float4 v = wp[e4];
        u16 h[4] __attribute__((aligned(8)));
        h[0]=f2bf(v.x); h[1]=f2bf(v.y); h[2]=f2bf(v.z); h[3]=f2bf(v.w);
        *(ushort4*)(wl + e4 * 4) = *(const ushort4*)h;
    }
    __syncthreads();
    u16* wo = wb + p * F_ * 32;
    for (int sid = tid; sid < 640; sid += 256) {
        int f = sid >> 2, k0 = (sid & 3) << 3;
        u16 tmp[8] __attribute__((aligned(16)));
#pragma unroll
        for (int j = 0; j < 8; ++j) tmp[j] = wl[(k0 + j) * F_ + f];
        *(uint4*)(wo + f * 32 + k0) = *(const uint4*)tmp;
    }
}

// One routing pass. MODE 0: c=0.1 uniform (MFMA-chained). MODE 1: t=u.v0 -> bias,
// softmax. MODE 2: t=bias+u.v1, softmax. bf16 partial s per block.
template<int MODE>
__global__ __launch_bounds__(NTHR, 4) void k_pass(
        const u16* __restrict__ xb, const u16* __restrict__ wb,
        const float* __restrict__ vprev, float* __restrict__ bias,
        u16* __restrict__ s_part)
{
    __shared__ u16 xt[128 * XS];   // 10240 B
    __shared__ u16 wt[F_ * WS];    // 12800 B
    const int tid = threadIdx.x, blk = blockIdx.x;
    const int L = tid & 63, wv = tid >> 6;
    const int q = L >> 4, col = L & 15;
    const int b = wv * 16 + col;
    const int p0 = blk * PPB;

    float4 vv[NC_];
    if (MODE != 0) {
#pragma unroll
        for (int n = 0; n < NC_; ++n)
            vv[n] = *(const float4*)(vprev + b * F_ + n * 16 + q * 4);
    }

    f32x4 s_acc[NC_];
#pragma unroll
    for (int n = 0; n < NC_; ++n) s_acc[n] = (f32x4){0.f, 0.f, 0.f, 0.f};

    // prefetch registers: x tile = 512 uint4, w tile = 640 uint4
    uint4 r0, r1, r2;
    {
        const uint4* xg = (const uint4*)(xb + p0 * 4096);
        const uint4* wg = (const uint4*)(wb + p0 * 5120);
        r0 = xg[tid]; r1 = wg[tid];
        if (tid < 128) r2 = wg[tid + 512];
    }

#pragma unroll
    for (int pp = 0; pp < PPB; ++pp) {
        __syncthreads();          // previous tile fully consumed
        *(uint4*)&xt[(tid >> 2) * XS + (tid & 3) * 8] = r0;
        *(uint4*)&wt[(tid >> 2) * WS + (tid & 3) * 8] = r1;
        if (tid < 128)
            *(uint4*)&wt[(128 + (tid >> 2)) * WS + (tid & 3) * 8] = r2;
        if (pp + 1 < PPB) {       // issue next tile's loads; they fly during compute
            const uint4* xg = (const uint4*)(xb + (p0 + pp + 1) * 4096);
            const uint4* wg = (const uint4*)(wb + (p0 + pp + 1) * 5120);
            r0 = xg[tid]; r1 = wg[tid];
            if (tid < 128) r2 = wg[tid + 512];
        }
        __syncthreads();          // tile visible

        bf16x8 bfrag = *(const bf16x8*)&xt[b * XS + q * 8];   // x[b][k=q*8+j]
        if (MODE == 0) {
#pragma unroll
            for (int n = 0; n < NC_; ++n) {
                bf16x8 afrag = *(const bf16x8*)&wt[(n * 16 + col) * WS + q * 8];
                s_acc[n] = __builtin_amdgcn_mfma_f32_16x16x32_bf16(afrag, bfrag, s_acc[n], 0, 0, 0);
            }
        } else {
            const int p = p0 + pp;
            float tt[NC_];
#pragma unroll
            for (int n = 0; n < NC_; ++n) {
                bf16x8 afrag = *(const bf16x8*)&wt[(n * 16 + col) * WS + q * 8];
                f32x4 z = {0.f, 0.f, 0.f, 0.f};
                f32x4 acc = __builtin_amdgcn_mfma_f32_16x16x32_bf16(afrag, bfrag, z, 0, 0, 0);
                float t = acc[0]*vv[n].x + acc[1]*vv[n].y + acc[2]*vv[n].z + acc[3]*vv[n].w;
                t += __shfl_xor(t, 16);   // full 16-elem dot over k'
                t += __shfl_xor(t, 32);
                if (MODE == 1) { if (q == (n & 3)) bias[(p * NC_ + n) * 128 + b] = t; }
                else           { t += bias[(p * NC_ + n) * 128 + b]; }
                tt[n] = t;
            }
            float mx = tt[0];
#pragma unroll
            for (int n = 1; n < NC_; ++n) mx = fmaxf(mx, tt[n]);
            float den = 0.f;
#pragma unroll
            for (int n = 0; n < NC_; ++n) { tt[n] = __expf(tt[n] - mx); den += tt[n]; }
            float inv = 1.f / den;
#pragma unroll
            for (int n = 0; n < NC_; ++n) {
                bf16x8 afrag = *(const bf16x8*)&wt[(n * 16 + col) * WS + q * 8];
                f32x4 z = {0.f, 0.f, 0.f, 0.f};
                f32x4 acc = __builtin_amdgcn_mfma_f32_16x16x32_bf16(afrag, bfrag, z, 0, 0, 0);
                float cf = tt[n] * inv;
#pragma unroll
                for (int r = 0; r < 4; ++r) s_acc[n][r] += cf * acc[r];
            }
        }
    }

    u16* sp = s_part + blk * (B_ * F_);
    const float sc = (MODE == 0) ? 0.1f : 1.f;
#pragma unroll
    for (int n = 0; n < NC_; ++n) {
        u16 h[4] __attribute__((aligned(8)));
#pragma unroll
        for (int r = 0; r < 4; ++r) h[r] = f2bf(s_acc[n][r] * sc);
        *(ushort4*)(sp + b * F_ + n * 16 + q * 4) = *(const ushort4*)h;
    }
}

// Sum bf16 partials over NBLK groups, squash along CLO=16, write fp32 v.
// 320 blocks x 256 thr; block owns 64 outputs (32 uint pairs), 8-way group split.
__global__ void k_red(const u16* __restrict__ s_part, float* __restrict__ vout) {
    __shared__ float r0s[256], r1s[256];
    const int tid = threadIdx.x, blk = blockIdx.x;
    const int pid = tid & 31, part = tid >> 5;
    const uint* sp = (const uint*)s_part;
    const int opair = blk * 32 + pid;           // 10240 pairs total
    float a0 = 0.f, a1 = 0.f;
#pragma unroll 8
    for (int g = part; g < NBLK; g += 8) {
        uint u = sp[g * 10240 + opair];
        a0 += bf2f((u16)(u & 0xffff));
        a1 += bf2f((u16)(u >> 16));
    }
    r0s[tid] = a0; r1s[tid] = a1;
    __syncthreads();
    if (tid < 32) {
        float s0 = 0.f, s1 = 0.f;
#pragma unroll
        for (int k = 0; k < 8; ++k) { s0 += r0s[k * 32 + tid]; s1 += r1s[k * 32 + tid]; }
        float sq = s0 * s0 + s1 * s1;
        sq += __shfl_xor(sq, 1);    // 8 lanes = 16 elems of one (b,n)
        sq += __shfl_xor(sq, 2);
        sq += __shfl_xor(sq, 4);
        float fct = sq / ((1.f + sq) * sqrtf(sq));
        float2 o = make_float2(s0 * fct, s1 * fct);
        *(float2*)(vout + 2 * (blk * 32 + tid)) = o;
    }
}

extern "C" void kernel_launch(void* const* d_in, const int* in_sizes, int n_in,
                              void* d_out, int out_size, void* d_ws, size_t ws_size,
                              hipStream_t stream) {
    const float* tensor = (const float*)d_in[0];
    const float* weight = (const float*)d_in[1];
    float* out = (float*)d_out;
    char* ws = (char*)d_ws;

    u16*   xb     = (u16*)(ws);                       // 16,777,216 B
    u16*   wb     = (u16*)(ws + 16777216);            // 20,971,520 B
    float* bias   = (float*)(ws + 37748736);          // 10,485,760 B
    u16*   s_part = (u16*)(ws + 48234496);            // 512*20480*2 = 20,971,520 B
    float* v0     = (float*)(ws + 69206016);          // 81,920 B
    float* v1     = (float*)(ws + 69287936);          // 81,920 B

    k_squash_x<<<4096, 256, 0, stream>>>(tensor, xb);
    k_wt<<<2048, 256, 0, stream>>>(weight, wb);

    k_pass<0><<<NBLK, NTHR, 0, stream>>>(xb, wb, nullptr, bias, s_part);
    k_red<<<320, 256, 0, stream>>>(s_part, v0);
    k_pass<1><<<NBLK, NTHR, 0, stream>>>(xb, wb, v0, bias, s_part);
    k_red<<<320, 256, 0, stream>>>(s_part, v1);
    k_pass<2><<<NBLK, NTHR, 0, stream>>>(xb, wb, v1, bias, s_part);
    k_red<<<320, 256, 0, stream>>>(s_part, out);
}

// Round 4
// 175.425 us; speedup vs baseline: 3.4801x; 1.6807x over previous
//
#include <hip/hip_runtime.h>

typedef unsigned short u16;
typedef __attribute__((ext_vector_type(8))) short bf16x8;
typedef __attribute__((ext_vector_type(4))) float f32x4;

#define B_   128
#define P_   2048
#define NC_  10
#define F_   160      // NC*CLO
#define NBLK 512      // k_pass blocks: 2 per CU
#define PPB  4        // p-tiles per block
#define NTHR 512
#define XS   40       // x tile row stride (shorts), padded
#define WS   40       // w tile row stride (shorts), padded

__device__ __forceinline__ u16 f2bf(float f) {
    union { float f; unsigned u; } v; v.f = f;
    unsigned r = v.u + 0x7FFFu + ((v.u >> 16) & 1u);   // RNE
    return (u16)(r >> 16);
}
__device__ __forceinline__ float bf2f(u16 h) {
    union { unsigned u; float f; } v; v.u = ((unsigned)h) << 16;
    return v.f;
}

// squash along NP=32, cast bf16, write xb[p][b][k]. 4 lanes per (b,p) pair.
__global__ void k_squash_x(const float* __restrict__ t, u16* __restrict__ xb) {
    int g = blockIdx.x * 256 + threadIdx.x;
    int pair = g >> 2, sub = g & 3;
    int p = pair & 2047, b = pair >> 11;
    const float4* tg = (const float4*)t;
    int fi = pair * 8 + sub * 2;
    float4 va = tg[fi], vb = tg[fi + 1];
    float ss = va.x*va.x + va.y*va.y + va.z*va.z + va.w*va.w
             + vb.x*vb.x + vb.y*vb.y + vb.z*vb.z + vb.w*vb.w;
    ss += __shfl_xor(ss, 1);      // quad holds the full 32-elem sum
    ss += __shfl_xor(ss, 2);
    float fct = ss / ((1.f + ss) * sqrtf(ss));
    u16 h[8] __attribute__((aligned(16)));
    h[0]=f2bf(va.x*fct); h[1]=f2bf(va.y*fct); h[2]=f2bf(va.z*fct); h[3]=f2bf(va.w*fct);
    h[4]=f2bf(vb.x*fct); h[5]=f2bf(vb.y*fct); h[6]=f2bf(vb.z*fct); h[7]=f2bf(vb.w*fct);
    *(uint4*)(xb + (p * 128 + b) * 32 + sub * 8) = *(const uint4*)h;
}

// weight[p][k][f] fp32 -> wb[p][f][k] bf16 (transpose via LDS)
__global__ void k_wt(const float* __restrict__ w, u16* __restrict__ wb) {
    __shared__ u16 wl[32 * F_];
    int p = blockIdx.x, tid = threadIdx.x;
    const float4* wp = (const float4*)(w + p * 32 * F_);
    for (int e4 = tid; e4 < 1280; e4 += 256) {
        float4 v = wp[e4];
        u16 h[4] __attribute__((aligned(8)));
        h[0]=f2bf(v.x); h[1]=f2bf(v.y); h[2]=f2bf(v.z); h[3]=f2bf(v.w);
        *(ushort4*)(wl + e4 * 4) = *(const ushort4*)h;
    }
    __syncthreads();
    u16* wo = wb + p * F_ * 32;
    for (int sid = tid; sid < 640; sid += 256) {
        int f = sid >> 2, k0 = (sid & 3) << 3;
        u16 tmp[8] __attribute__((aligned(16)));
#pragma unroll
        for (int j = 0; j < 8; ++j) tmp[j] = wl[(k0 + j) * F_ + f];
        *(uint4*)(wo + f * 32 + k0) = *(const uint4*)tmp;
    }
}

// One routing pass. MODE 0: c=0.1 uniform (MFMA-chained). MODE>=1: logits are
// t = u.vprev (vprev = v0 for pass 1, v0+v1 for pass 2 -- bias array eliminated
// algebraically: bias_k = u.(sum of previous v's)), softmax over n, weighted sum.
template<int MODE>
__global__ __launch_bounds__(NTHR, 2) void k_pass(
        const u16* __restrict__ xb, const u16* __restrict__ wb,
        const float* __restrict__ vprev, u16* __restrict__ s_part)
{
    __shared__ u16 xt[128 * XS];   // 10240 B
    __shared__ u16 wt[F_ * WS];    // 12800 B
    const int tid = threadIdx.x, blk = blockIdx.x;
    const int L = tid & 63, wv = tid >> 6;
    const int q = L >> 4, col = L & 15;
    const int b = wv * 16 + col;
    const int p0 = blk * PPB;

    float4 vv[NC_];
    if (MODE != 0) {
#pragma unroll
        for (int n = 0; n < NC_; ++n)
            vv[n] = *(const float4*)(vprev + b * F_ + n * 16 + q * 4);
    }

    f32x4 s_acc[NC_];
#pragma unroll
    for (int n = 0; n < NC_; ++n) s_acc[n] = (f32x4){0.f, 0.f, 0.f, 0.f};

    // prefetch registers: x tile = 512 uint4, w tile = 640 uint4
    uint4 r0, r1, r2;
    {
        const uint4* xg = (const uint4*)(xb + p0 * 4096);
        const uint4* wg = (const uint4*)(wb + p0 * 5120);
        r0 = xg[tid]; r1 = wg[tid];
        if (tid < 128) r2 = wg[tid + 512];
    }

#pragma unroll
    for (int pp = 0; pp < PPB; ++pp) {
        __syncthreads();          // previous tile fully consumed
        *(uint4*)&xt[(tid >> 2) * XS + (tid & 3) * 8] = r0;
        *(uint4*)&wt[(tid >> 2) * WS + (tid & 3) * 8] = r1;
        if (tid < 128)
            *(uint4*)&wt[(128 + (tid >> 2)) * WS + (tid & 3) * 8] = r2;
        if (pp + 1 < PPB) {       // next tile's loads fly during compute
            const uint4* xg = (const uint4*)(xb + (p0 + pp + 1) * 4096);
            const uint4* wg = (const uint4*)(wb + (p0 + pp + 1) * 5120);
            r0 = xg[tid]; r1 = wg[tid];
            if (tid < 128) r2 = wg[tid + 512];
        }
        __syncthreads();          // tile visible

        bf16x8 bfrag = *(const bf16x8*)&xt[b * XS + q * 8];   // x[b][k=q*8+j]
        if (MODE == 0) {
#pragma unroll
            for (int n = 0; n < NC_; ++n) {
                bf16x8 afrag = *(const bf16x8*)&wt[(n * 16 + col) * WS + q * 8];
                s_acc[n] = __builtin_amdgcn_mfma_f32_16x16x32_bf16(afrag, bfrag, s_acc[n], 0, 0, 0);
            }
        } else {
            float tt[NC_];
#pragma unroll
            for (int n = 0; n < NC_; ++n) {
                bf16x8 afrag = *(const bf16x8*)&wt[(n * 16 + col) * WS + q * 8];
                f32x4 z = {0.f, 0.f, 0.f, 0.f};
                f32x4 acc = __builtin_amdgcn_mfma_f32_16x16x32_bf16(afrag, bfrag, z, 0, 0, 0);
                float t = acc[0]*vv[n].x + acc[1]*vv[n].y + acc[2]*vv[n].z + acc[3]*vv[n].w;
                t += __shfl_xor(t, 16);   // full 16-elem dot over k'
                t += __shfl_xor(t, 32);
                tt[n] = t;
            }
            float mx = tt[0];
#pragma unroll
            for (int n = 1; n < NC_; ++n) mx = fmaxf(mx, tt[n]);
            float den = 0.f;
#pragma unroll
            for (int n = 0; n < NC_; ++n) { tt[n] = __expf(tt[n] - mx); den += tt[n]; }
            float inv = 1.f / den;
#pragma unroll
            for (int n = 0; n < NC_; ++n) {
                bf16x8 afrag = *(const bf16x8*)&wt[(n * 16 + col) * WS + q * 8];
                f32x4 z = {0.f, 0.f, 0.f, 0.f};
                f32x4 acc = __builtin_amdgcn_mfma_f32_16x16x32_bf16(afrag, bfrag, z, 0, 0, 0);
                float cf = tt[n] * inv;
#pragma unroll
                for (int r = 0; r < 4; ++r) s_acc[n][r] += cf * acc[r];
            }
        }
    }

    u16* sp = s_part + blk * (B_ * F_);
    const float sc = (MODE == 0) ? 0.1f : 1.f;
#pragma unroll
    for (int n = 0; n < NC_; ++n) {
        u16 h[4] __attribute__((aligned(8)));
#pragma unroll
        for (int r = 0; r < 4; ++r) h[r] = f2bf(s_acc[n][r] * sc);
        *(ushort4*)(sp + b * F_ + n * 16 + q * 4) = *(const ushort4*)h;
    }
}

// Sum bf16 partials over NBLK groups, squash along CLO=16.
// ADD: write squash(s) + vprev (produces v0+v1 for the next pass's logits).
template<int ADD>
__global__ void k_red(const u16* __restrict__ s_part,
                      const float* __restrict__ vprev, float* __restrict__ vout) {
    __shared__ float r0s[256], r1s[256];
    const int tid = threadIdx.x, blk = blockIdx.x;
    const int pid = tid & 31, part = tid >> 5;
    const uint* sp = (const uint*)s_part;
    const int opair = blk * 32 + pid;           // 10240 pairs total
    float a0 = 0.f, a1 = 0.f;
#pragma unroll 8
    for (int g = part; g < NBLK; g += 8) {
        uint u = sp[g * 10240 + opair];
        a0 += bf2f((u16)(u & 0xffff));
        a1 += bf2f((u16)(u >> 16));
    }
    r0s[tid] = a0; r1s[tid] = a1;
    __syncthreads();
    if (tid < 32) {
        float s0 = 0.f, s1 = 0.f;
#pragma unroll
        for (int k = 0; k < 8; ++k) { s0 += r0s[k * 32 + tid]; s1 += r1s[k * 32 + tid]; }
        float sq = s0 * s0 + s1 * s1;
        sq += __shfl_xor(sq, 1);    // 8 lanes = 16 elems of one (b,n)
        sq += __shfl_xor(sq, 2);
        sq += __shfl_xor(sq, 4);
        float fct = sq / ((1.f + sq) * sqrtf(sq));
        float2 o = make_float2(s0 * fct, s1 * fct);
        if (ADD) {
            float2 pv = *(const float2*)(vprev + 2 * (blk * 32 + tid));
            o.x += pv.x; o.y += pv.y;
        }
        *(float2*)(vout + 2 * (blk * 32 + tid)) = o;
    }
}

extern "C" void kernel_launch(void* const* d_in, const int* in_sizes, int n_in,
                              void* d_out, int out_size, void* d_ws, size_t ws_size,
                              hipStream_t stream) {
    const float* tensor = (const float*)d_in[0];
    const float* weight = (const float*)d_in[1];
    float* out = (float*)d_out;
    char* ws = (char*)d_ws;

    u16*   xb     = (u16*)(ws);                       // 16,777,216 B
    u16*   wb     = (u16*)(ws + 16777216);            // 20,971,520 B
    u16*   s_part = (u16*)(ws + 37748736);            // 512*20480*2 = 20,971,520 B
    float* v0     = (float*)(ws + 58720256);          // 81,920 B
    float* vs     = (float*)(ws + 58802176);          // 81,920 B (v0 + v1)

    k_squash_x<<<4096, 256, 0, stream>>>(tensor, xb);
    k_wt<<<2048, 256, 0, stream>>>(weight, wb);

    k_pass<0><<<NBLK, NTHR, 0, stream>>>(xb, wb, nullptr, s_part);
    k_red<0><<<320, 256, 0, stream>>>(s_part, nullptr, v0);
    k_pass<1><<<NBLK, NTHR, 0, stream>>>(xb, wb, v0, s_part);
    k_red<1><<<320, 256, 0, stream>>>(s_part, v0, vs);
    k_pass<2><<<NBLK, NTHR, 0, stream>>>(xb, wb, vs, s_part);
    k_red<0><<<320, 256, 0, stream>>>(s_part, nullptr, out);
}